// Round 12
// baseline (152.066 us; speedup 1.0000x reference)
//
#include <hip/hip_runtime.h>
#include <hip/hip_bf16.h>
#include <math.h>

typedef unsigned long long u64;
typedef unsigned int u32;

#define C_NUM 80
#define TOPK 1000
#define CAP 2048
#define HB 128
#define STG 32
#define NCHUNK 16
#define SCORE_THR 0.05f
#define IOU_THR 0.5f
#define GRID_SCAN 256

// correctly-rounded-ish f32 exp via double (matched reference bit-exact rounds 1-11)
__device__ __forceinline__ float exp_cr(float x) {
    return (float)exp((double)x);
}

__device__ __forceinline__ u64 readlane64(u64 v, int l) {
    u32 lo = (u32)__builtin_amdgcn_readlane((int)(u32)v, l);
    u32 hi = (u32)__builtin_amdgcn_readlane((int)(u32)(v >> 32), l);
    return ((u64)hi << 32) | lo;
}

// Exact f32 replication of reference decode + clip (no FMA contraction).
__device__ __forceinline__ void decode_box(const float* __restrict__ anch,
                                           const float* __restrict__ reg,
                                           int a, float fw, float fh, float4* out) {
#pragma clang fp contract(off)
    float a0 = anch[(size_t)a * 4 + 0], a1 = anch[(size_t)a * 4 + 1];
    float a2 = anch[(size_t)a * 4 + 2], a3 = anch[(size_t)a * 4 + 3];
    float d0 = reg[(size_t)a * 4 + 0], d1 = reg[(size_t)a * 4 + 1];
    float d2 = reg[(size_t)a * 4 + 2], d3 = reg[(size_t)a * 4 + 3];
    float w = a2 - a0, h = a3 - a1;
    float cx = a0 + 0.5f * w, cy = a1 + 0.5f * h;
    float dx = d0 * 0.1f, dy = d1 * 0.1f, dw = d2 * 0.2f, dh = d3 * 0.2f;
    float t1 = dx * w; float pcx = cx + t1;
    float t2 = dy * h; float pcy = cy + t2;
    float pw = exp_cr(dw) * w;
    float ph = exp_cr(dh) * h;
    float x1 = pcx - 0.5f * pw, y1 = pcy - 0.5f * ph;
    float x2 = pcx + 0.5f * pw, y2 = pcy + 0.5f * ph;
    x1 = fminf(fmaxf(x1, 0.0f), fw);
    y1 = fminf(fmaxf(y1, 0.0f), fh);
    x2 = fminf(fmaxf(x2, 0.0f), fw);
    y2 = fminf(fmaxf(y2, 0.0f), fh);
    *out = make_float4(x1, y1, x2, y2);
}

// Per-block private histogram slices; no global atomics at all.
__global__ __launch_bounds__(1024)
void hist_kernel(const float4* __restrict__ cls4, u32* __restrict__ slices, int nvec) {
    __shared__ u32 h[C_NUM * HB];                 // 40 KB
    int tid = threadIdx.x;
    for (int i = tid; i < C_NUM * HB; i += 1024) h[i] = 0u;
    __syncthreads();
    int gid = blockIdx.x * 1024 + tid;
    const int stride = GRID_SCAN * 1024;          // float4 units
    const int dC = (stride * 4) % C_NUM;
    int c0 = (gid * 4) % C_NUM;
    for (int v = gid; v < nvec; v += stride) {
        float4 f = cls4[v];
        float e[4] = {f.x, f.y, f.z, f.w};
        int cc = c0;
#pragma unroll
        for (int k = 0; k < 4; ++k) {
            int t = (((int)__float_as_uint(e[k])) - 0x3F000000) >> 16;
            if (t > 0) {
                t = t > HB - 1 ? HB - 1 : t;
                atomicAdd(&h[cc * HB + t], 1u);   // LDS atomic only
            }
            cc++; if (cc == C_NUM) cc = 0;
        }
        c0 += dC; if (c0 >= C_NUM) c0 -= C_NUM;
    }
    __syncthreads();
    u32* my = slices + (size_t)blockIdx.x * (C_NUM * HB);
    for (int i = tid; i < C_NUM * HB; i += 1024) my[i] = h[i];
}

// Per-class: parallel reduce of 256 slices (8 groups x 128 buckets) -> suffix-sum
// -> threshold bit-edge.
__global__ __launch_bounds__(1024)
void thr_kernel(const u32* __restrict__ slices, u32* __restrict__ thrG) {
    __shared__ u32 part[8][HB];
    __shared__ u32 s[HB];
    __shared__ int bsel;
    int c = blockIdx.x, tid = threadIdx.x;
    int b = tid & (HB - 1), g = tid >> 7;         // 8 groups of 32 slices each
    u32 sum = 0;
    const u32* base = slices + c * HB + b;
    for (int sl = g * 32; sl < g * 32 + 32; ++sl)
        sum += base[(size_t)sl * (C_NUM * HB)];   // lanes read consecutive -> coalesced
    part[g][b] = sum;
    if (tid == 0) bsel = 0;
    __syncthreads();
    if (tid < HB) {
        u32 t = 0;
#pragma unroll
        for (int g2 = 0; g2 < 8; ++g2) t += part[g2][tid];
        s[tid] = t;
    }
    __syncthreads();
    for (int d = 1; d < HB; d <<= 1) {
        u32 v = 0;
        if (tid < HB) v = s[tid] + ((tid + d < HB) ? s[tid + d] : 0u);
        __syncthreads();
        if (tid < HB) s[tid] = v;
        __syncthreads();
    }
    if (tid < HB) {
        u32 me = s[tid];
        u32 nxt = (tid < HB - 1) ? s[tid + 1] : 0u;
        if (me >= (u32)TOPK && (tid == HB - 1 || nxt < (u32)TOPK)) bsel = tid;
    }
    __syncthreads();
    if (tid == 0) {
        int bb = bsel;
        thrG[c] = (bb == 0) ? 0u : (u32)(0x3F000000 + (bb << 16));
    }
}

// Gather with block-local LDS staging; ONE bulk reservation atomic per (class,block).
__global__ __launch_bounds__(1024)
void gather_kernel(const float4* __restrict__ cls4, const u32* __restrict__ thrG,
                   u32* __restrict__ cntG, u64* __restrict__ pool, int nvec) {
    __shared__ int thrS[C_NUM];
    __shared__ u32 lcnt[C_NUM];
    __shared__ u32 lbase[C_NUM];
    __shared__ u64 stage[C_NUM * STG];            // 20 KB
    int tid = threadIdx.x;
    if (tid < C_NUM) { thrS[tid] = (int)thrG[tid]; lcnt[tid] = 0u; }
    __syncthreads();

    int gid = blockIdx.x * 1024 + tid;
    const int stride = GRID_SCAN * 1024;
    const int dA = (stride * 4) / C_NUM;
    const int dC = (stride * 4) % C_NUM;
    int base = gid * 4;
    int aa0 = base / C_NUM;
    int c0 = base - aa0 * C_NUM;
    for (int v = gid; v < nvec; v += stride) {
        float4 f = cls4[v];
        float e[4] = {f.x, f.y, f.z, f.w};
        int cc = c0, aa = aa0;
#pragma unroll
        for (int k = 0; k < 4; ++k) {
            int bits = (int)__float_as_uint(e[k]);
            if (bits >= thrS[cc]) {
                u64 key = ((u64)(u32)bits << 32) | (u64)(u32)(~(u32)aa);
                u32 p = atomicAdd(&lcnt[cc], 1u);             // LDS atomic
                if (p < STG) stage[cc * STG + p] = key;
                else {                                         // rare overflow fallback
                    u32 q = atomicAdd(&cntG[cc], 1u);
                    if (q < CAP) pool[(size_t)cc * CAP + q] = key;
                }
            }
            cc++; if (cc == C_NUM) { cc = 0; aa++; }
        }
        c0 += dC;
        if (c0 >= C_NUM) { c0 -= C_NUM; aa0 += dA + 1; } else aa0 += dA;
    }
    __syncthreads();
    if (tid < C_NUM) {
        u32 nl = lcnt[tid]; if (nl > STG) nl = STG;
        lbase[tid] = nl ? atomicAdd(&cntG[tid], nl) : 0u;      // one atomic per class
        lcnt[tid] = nl;
    }
    __syncthreads();
    for (int i = tid; i < C_NUM * STG; i += 1024) {
        int c = i >> 5, k = i & (STG - 1);
        if ((u32)k < lcnt[c]) {
            u32 q = lbase[c] + (u32)k;
            if (q < CAP) pool[(size_t)c * CAP + q] = stage[i];
        }
    }
}

// Rank-sort spread over all CUs: grid (C_NUM, 8) x 256. Also zero-fills the
// tail slots [n, TOPK).
__global__ __launch_bounds__(256)
void rank_kernel(const u64* __restrict__ pool, const u32* __restrict__ cntG,
                 const float* __restrict__ anchors, const float* __restrict__ regs,
                 const int* __restrict__ imh, const int* __restrict__ imw,
                 u64* __restrict__ sortedKey, float4* __restrict__ candBox,
                 float* __restrict__ candArea) {
    __shared__ __align__(16) u64 keys[CAP];       // 16 KB
    int c = blockIdx.x, q = blockIdx.y, tid = threadIdx.x;
    int n = (int)cntG[c]; if (n > CAP) n = CAP;
    int my = q * 256 + tid;
    if (my >= n && my < TOPK) {                    // tail zero-fill
        int g = c * TOPK + my;
        sortedKey[g] = 0ull;
        candBox[g] = make_float4(0.f, 0.f, 0.f, 0.f);
        candArea[g] = 0.f;
    }
    if (q * 256 >= n) return;                      // uniform: whole block done
    for (int i = tid; i < n; i += 256) keys[i] = pool[(size_t)c * CAP + i];
    __syncthreads();
    u64 k0 = (my < n) ? keys[my] : ~0ull;          // sentinel: rank 0, write-guarded
    int r0 = 0;
    int j = 0;
    for (; j + 8 <= n; j += 8) {
        ulonglong2 p0 = *(const ulonglong2*)&keys[j];
        ulonglong2 p1 = *(const ulonglong2*)&keys[j + 2];
        ulonglong2 p2 = *(const ulonglong2*)&keys[j + 4];
        ulonglong2 p3 = *(const ulonglong2*)&keys[j + 6];
        r0 += (int)(p0.x > k0) + (int)(p0.y > k0)
            + (int)(p1.x > k0) + (int)(p1.y > k0)
            + (int)(p2.x > k0) + (int)(p2.y > k0)
            + (int)(p3.x > k0) + (int)(p3.y > k0);
    }
    for (; j < n; ++j) r0 += (int)(keys[j] > k0);
    if (my < n && r0 < TOPK) {
        float sc = __uint_as_float((u32)(k0 >> 32));
        int a = (int)(~(u32)k0);
        float fw = (float)(*imw), fh = (float)(*imh);
        float4 bx = make_float4(0.f, 0.f, 0.f, 0.f);
        if (sc > SCORE_THR) decode_box(anchors, regs, a, fw, fh, &bx);
        int g = c * TOPK + r0;
        sortedKey[g] = k0;
        candBox[g] = bx;
        candArea[g] = fmaxf(bx.z - bx.x, 0.0f) * fmaxf(bx.w - bx.y, 0.0f);
    }
}

// Suppression bit-matrix, TRANSPOSED store: supT[c][jw][i] = 64-bit word jw of
// row i (bit j-in-word set iff j>i && iou(i,j)>0.5). Register-resident columns;
// only rows/cols >= rowBase staged into LDS (block q never reads below it).
// Division eliminated: RN32(inter/d) > 0.5f  <=>  inter > (0.5+2^-25)*d (exact in
// double, tie unreachable for f32 operands) -> decisions bit-identical.
__global__ __launch_bounds__(256)
void iou_kernel(const float4* __restrict__ candBox, const float* __restrict__ candArea,
                u64* __restrict__ supT) {
#pragma clang fp contract(off)
    __shared__ float4 box[NCHUNK * 64];           // 16 KB (padded to 1024)
    __shared__ float area[NCHUNK * 64];           //  4 KB
    int c = blockIdx.x, q = blockIdx.y;
    int tid = threadIdx.x, lane = tid & 63, wave = tid >> 6;
    int rowBase = q << 6;
    for (int i = rowBase + tid; i < NCHUNK * 64; i += 256) {
        if (i < TOPK) {
            box[i] = candBox[(size_t)c * TOPK + i];
            area[i] = candArea[(size_t)c * TOPK + i];
        } else {
            box[i] = make_float4(0.f, 0.f, 0.f, 0.f);
            area[i] = 0.f;
        }
    }
    __syncthreads();

    int rowEnd = TOPK - rowBase; if (rowEnd > 64) rowEnd = 64;   // 40 for q=15
    const double CC = 0.5 + 0x1p-25;
    u64* colBase = supT + (size_t)c * (NCHUNK * 1024) + rowBase;

    for (int jw = q + wave; jw < NCHUNK; jw += 4) {
        int j = (jw << 6) | lane;
        float4 bj = box[j];                        // register-resident column
        float aj = area[j];
        u64 vw = 0ull;
#pragma unroll 8
        for (int r = 0; r < 64; ++r) {
            int i = rowBase + r;
            float4 bi = box[i];                    // uniform -> LDS broadcast
            float ai = area[i];
            float ltx = fmaxf(bi.x, bj.x), lty = fmaxf(bi.y, bj.y);
            float rbx = fminf(bi.z, bj.z), rby = fminf(bi.w, bj.w);
            float ww = fmaxf(rbx - ltx, 0.0f), hh = fmaxf(rby - lty, 0.0f);
            float inter = ww * hh;
            float uni = (ai + aj) - inter;
            float d = fmaxf(uni, 1e-8f);
            bool sup = (double)inter > CC * (double)d;
            u64 w64 = __ballot(sup);
            if (jw == q) w64 &= (((~0ull) << 1) << r);   // keep j>i only
            vw = (lane == r) ? w64 : vw;
        }
        if (lane < rowEnd) colBase[(size_t)jw * 1024 + lane] = vw;
    }
}

// Greedy NMS + output, one 1024-thread block per class.
// Phase 1: 1024 threads cooperatively stream the ~69 KB upper-triangle of the
// class's sup matrix into LDS -- thousands of independent u64 loads in flight
// (the MLP that the 64-thread register version couldn't create). One barrier.
// Phase 2: 16-wave chunk loop entirely from LDS: wave w runs the intra-chunk
// closure (readlane chain on a register loaded from LDS), barrier (no vmcnt
// pending -> cheap), waves t>w apply cross-chunk suppression via masked 6-step
// shfl_xor OR-reduce of their coalesced LDS column read. Rows >= TOPK hold
// garbage LDS but their keep bits start 0 and row & -(bit) with bit=0 is a
// no-op -> bit-identical decisions.
__global__ __launch_bounds__(1024)
void nmsout_kernel(const u64* __restrict__ supT, const u64* __restrict__ sortedKey,
                   const float4* __restrict__ candBox, float* __restrict__ out) {
    __shared__ __align__(16) u64 supLds[NCHUNK * 1024];   // 128 KB (triangle filled)
    __shared__ u64 km[NCHUNK];
    int c = blockIdx.x, tid = threadIdx.x;
    int lane = tid & 63, wave = tid >> 6;

    const u64* base = supT + (size_t)c * (NCHUNK * 1024);
#pragma unroll
    for (int jw = 0; jw < NCHUNK; ++jw) {
        int R = (jw + 1) << 6; if (R > TOPK) R = TOPK;    // rows with word jw
        for (int i = tid; i < R; i += 1024)
            supLds[jw * 1024 + i] = base[(size_t)jw * 1024 + i];
    }

    u64 key = (tid < TOPK) ? sortedKey[c * TOPK + tid] : 0ull;
    float sc = __uint_as_float((u32)(key >> 32));
    bool valid = (tid < TOPK) && (sc > SCORE_THR);
    u64 kw = __ballot(valid);                       // wave t's keep word, uniform
    __syncthreads();

    for (int w = 0; w < NCHUNK; ++w) {
        if (wave == w) {
            u64 v = supLds[w * 1024 + (w << 6) + lane];   // row (64w+lane), word w
            u64 am = kw;
#pragma unroll
            for (int i = 0; i < 64; ++i) {
                u64 row = readlane64(v, i);
                am &= ~(row & (0ull - ((am >> i) & 1ull)));
            }
            kw = am;
            if (lane == 0) km[w] = am;
        }
        __syncthreads();
        if (wave > w) {
            u64 kmw = km[w];                              // uniform LDS broadcast
            u64 v = supLds[wave * 1024 + (w << 6) + lane]; // row (64w+lane), word 'wave'
            u64 masked = ((kmw >> lane) & 1ull) ? v : 0ull;
            u32 mlo = (u32)masked, mhi = (u32)(masked >> 32);
#pragma unroll
            for (int s = 1; s < 64; s <<= 1) {
                mlo |= __shfl_xor(mlo, s);
                mhi |= __shfl_xor(mhi, s);
            }
            kw &= ~(((u64)mhi << 32) | mlo);
        }
    }

    if (tid < TOPK) {
        bool keep = (kw >> lane) & 1ull;
        int g = c * TOPK + tid;
        out[g] = keep ? sc : 0.0f;
        out[C_NUM * TOPK + g] = keep ? (float)c : -1.0f;
        float4 b = keep ? candBox[(size_t)c * TOPK + tid]
                        : make_float4(0.f, 0.f, 0.f, 0.f);
        ((float4*)(out + 2 * C_NUM * TOPK))[g] = b;
    }
}

extern "C" void kernel_launch(void* const* d_in, const int* in_sizes, int n_in,
                              void* d_out, int out_size, void* d_ws, size_t ws_size,
                              hipStream_t stream) {
    const float* cls  = (const float*)d_in[0];
    const float* reg  = (const float*)d_in[1];
    const float* anch = (const float*)d_in[2];
    const int* imh    = (const int*)d_in[3];
    const int* imw    = (const int*)d_in[4];
    int A = in_sizes[2] / 4;
    int nvec = (A * C_NUM) / 4;

    char* w = (char*)d_ws;
    size_t off = 0;
    auto alloc = [&](size_t bytes) -> void* {
        off = (off + 255) & ~(size_t)255;
        void* p = w + off;
        off += bytes;
        return p;
    };
    u32*    cntG      = (u32*)   alloc((size_t)C_NUM * 4);
    u32*    thrG      = (u32*)   alloc((size_t)C_NUM * 4);
    u32*    slices    = (u32*)   alloc((size_t)GRID_SCAN * C_NUM * HB * 4);   // 10.5 MB
    u64*    pool      = (u64*)   alloc((size_t)C_NUM * CAP * 8);              // 1.3 MB
    u64*    sortedKey = (u64*)   alloc((size_t)C_NUM * TOPK * 8);
    float4* candBox   = (float4*)alloc((size_t)C_NUM * TOPK * 16);
    float*  candArea  = (float*) alloc((size_t)C_NUM * TOPK * 4);
    u64*    supT      = (u64*)   alloc((size_t)C_NUM * NCHUNK * 1024 * 8);    // 10.5 MB

    hipMemsetAsync(cntG, 0, (size_t)C_NUM * 4, stream);
    hist_kernel<<<GRID_SCAN, 1024, 0, stream>>>((const float4*)cls, slices, nvec);
    thr_kernel<<<C_NUM, 1024, 0, stream>>>(slices, thrG);
    gather_kernel<<<GRID_SCAN, 1024, 0, stream>>>((const float4*)cls, thrG, cntG, pool, nvec);
    rank_kernel<<<dim3(C_NUM, 8), 256, 0, stream>>>(pool, cntG, anch, reg, imh, imw,
                                                    sortedKey, candBox, candArea);
    iou_kernel<<<dim3(C_NUM, NCHUNK), 256, 0, stream>>>(candBox, candArea, supT);
    nmsout_kernel<<<C_NUM, 1024, 0, stream>>>(supT, sortedKey, candBox, (float*)d_out);
}

// Round 13
// 151.796 us; speedup vs baseline: 1.0018x; 1.0018x over previous
//
#include <hip/hip_runtime.h>
#include <hip/hip_bf16.h>
#include <math.h>

typedef unsigned long long u64;
typedef unsigned int u32;

#define C_NUM 80
#define TOPK 1000
#define CAP 2048
#define HB 128
#define STG 32
#define NCHUNK 16
#define SCORE_THR 0.05f
#define IOU_THR 0.5f
#define GRID_SCAN 256

// correctly-rounded-ish f32 exp via double (matched reference bit-exact rounds 1-11)
__device__ __forceinline__ float exp_cr(float x) {
    return (float)exp((double)x);
}

__device__ __forceinline__ u64 readlane64(u64 v, int l) {
    u32 lo = (u32)__builtin_amdgcn_readlane((int)(u32)v, l);
    u32 hi = (u32)__builtin_amdgcn_readlane((int)(u32)(v >> 32), l);
    return ((u64)hi << 32) | lo;
}

// Exact f32 replication of reference decode + clip (no FMA contraction).
__device__ __forceinline__ void decode_box(const float* __restrict__ anch,
                                           const float* __restrict__ reg,
                                           int a, float fw, float fh, float4* out) {
#pragma clang fp contract(off)
    float a0 = anch[(size_t)a * 4 + 0], a1 = anch[(size_t)a * 4 + 1];
    float a2 = anch[(size_t)a * 4 + 2], a3 = anch[(size_t)a * 4 + 3];
    float d0 = reg[(size_t)a * 4 + 0], d1 = reg[(size_t)a * 4 + 1];
    float d2 = reg[(size_t)a * 4 + 2], d3 = reg[(size_t)a * 4 + 3];
    float w = a2 - a0, h = a3 - a1;
    float cx = a0 + 0.5f * w, cy = a1 + 0.5f * h;
    float dx = d0 * 0.1f, dy = d1 * 0.1f, dw = d2 * 0.2f, dh = d3 * 0.2f;
    float t1 = dx * w; float pcx = cx + t1;
    float t2 = dy * h; float pcy = cy + t2;
    float pw = exp_cr(dw) * w;
    float ph = exp_cr(dh) * h;
    float x1 = pcx - 0.5f * pw, y1 = pcy - 0.5f * ph;
    float x2 = pcx + 0.5f * pw, y2 = pcy + 0.5f * ph;
    x1 = fminf(fmaxf(x1, 0.0f), fw);
    y1 = fminf(fmaxf(y1, 0.0f), fh);
    x2 = fminf(fmaxf(x2, 0.0f), fw);
    y2 = fminf(fmaxf(y2, 0.0f), fh);
    *out = make_float4(x1, y1, x2, y2);
}

// Per-block private histogram slices; no global atomics at all.
__global__ __launch_bounds__(1024)
void hist_kernel(const float4* __restrict__ cls4, u32* __restrict__ slices, int nvec) {
    __shared__ u32 h[C_NUM * HB];                 // 40 KB
    int tid = threadIdx.x;
    for (int i = tid; i < C_NUM * HB; i += 1024) h[i] = 0u;
    __syncthreads();
    int gid = blockIdx.x * 1024 + tid;
    const int stride = GRID_SCAN * 1024;          // float4 units
    const int dC = (stride * 4) % C_NUM;
    int c0 = (gid * 4) % C_NUM;
    for (int v = gid; v < nvec; v += stride) {
        float4 f = cls4[v];
        float e[4] = {f.x, f.y, f.z, f.w};
        int cc = c0;
#pragma unroll
        for (int k = 0; k < 4; ++k) {
            int t = (((int)__float_as_uint(e[k])) - 0x3F000000) >> 16;
            if (t > 0) {
                t = t > HB - 1 ? HB - 1 : t;
                atomicAdd(&h[cc * HB + t], 1u);   // LDS atomic only
            }
            cc++; if (cc == C_NUM) cc = 0;
        }
        c0 += dC; if (c0 >= C_NUM) c0 -= C_NUM;
    }
    __syncthreads();
    u32* my = slices + (size_t)blockIdx.x * (C_NUM * HB);
    for (int i = tid; i < C_NUM * HB; i += 1024) my[i] = h[i];
}

// Per-class: parallel reduce of 256 slices (8 groups x 128 buckets) -> suffix-sum
// -> threshold bit-edge.
__global__ __launch_bounds__(1024)
void thr_kernel(const u32* __restrict__ slices, u32* __restrict__ thrG) {
    __shared__ u32 part[8][HB];
    __shared__ u32 s[HB];
    __shared__ int bsel;
    int c = blockIdx.x, tid = threadIdx.x;
    int b = tid & (HB - 1), g = tid >> 7;         // 8 groups of 32 slices each
    u32 sum = 0;
    const u32* base = slices + c * HB + b;
    for (int sl = g * 32; sl < g * 32 + 32; ++sl)
        sum += base[(size_t)sl * (C_NUM * HB)];   // lanes read consecutive -> coalesced
    part[g][b] = sum;
    if (tid == 0) bsel = 0;
    __syncthreads();
    if (tid < HB) {
        u32 t = 0;
#pragma unroll
        for (int g2 = 0; g2 < 8; ++g2) t += part[g2][tid];
        s[tid] = t;
    }
    __syncthreads();
    for (int d = 1; d < HB; d <<= 1) {
        u32 v = 0;
        if (tid < HB) v = s[tid] + ((tid + d < HB) ? s[tid + d] : 0u);
        __syncthreads();
        if (tid < HB) s[tid] = v;
        __syncthreads();
    }
    if (tid < HB) {
        u32 me = s[tid];
        u32 nxt = (tid < HB - 1) ? s[tid + 1] : 0u;
        if (me >= (u32)TOPK && (tid == HB - 1 || nxt < (u32)TOPK)) bsel = tid;
    }
    __syncthreads();
    if (tid == 0) {
        int bb = bsel;
        thrG[c] = (bb == 0) ? 0u : (u32)(0x3F000000 + (bb << 16));
    }
}

// Gather with block-local LDS staging; ONE bulk reservation atomic per (class,block).
__global__ __launch_bounds__(1024)
void gather_kernel(const float4* __restrict__ cls4, const u32* __restrict__ thrG,
                   u32* __restrict__ cntG, u64* __restrict__ pool, int nvec) {
    __shared__ int thrS[C_NUM];
    __shared__ u32 lcnt[C_NUM];
    __shared__ u32 lbase[C_NUM];
    __shared__ u64 stage[C_NUM * STG];            // 20 KB
    int tid = threadIdx.x;
    if (tid < C_NUM) { thrS[tid] = (int)thrG[tid]; lcnt[tid] = 0u; }
    __syncthreads();

    int gid = blockIdx.x * 1024 + tid;
    const int stride = GRID_SCAN * 1024;
    const int dA = (stride * 4) / C_NUM;
    const int dC = (stride * 4) % C_NUM;
    int base = gid * 4;
    int aa0 = base / C_NUM;
    int c0 = base - aa0 * C_NUM;
    for (int v = gid; v < nvec; v += stride) {
        float4 f = cls4[v];
        float e[4] = {f.x, f.y, f.z, f.w};
        int cc = c0, aa = aa0;
#pragma unroll
        for (int k = 0; k < 4; ++k) {
            int bits = (int)__float_as_uint(e[k]);
            if (bits >= thrS[cc]) {
                u64 key = ((u64)(u32)bits << 32) | (u64)(u32)(~(u32)aa);
                u32 p = atomicAdd(&lcnt[cc], 1u);             // LDS atomic
                if (p < STG) stage[cc * STG + p] = key;
                else {                                         // rare overflow fallback
                    u32 q = atomicAdd(&cntG[cc], 1u);
                    if (q < CAP) pool[(size_t)cc * CAP + q] = key;
                }
            }
            cc++; if (cc == C_NUM) { cc = 0; aa++; }
        }
        c0 += dC;
        if (c0 >= C_NUM) { c0 -= C_NUM; aa0 += dA + 1; } else aa0 += dA;
    }
    __syncthreads();
    if (tid < C_NUM) {
        u32 nl = lcnt[tid]; if (nl > STG) nl = STG;
        lbase[tid] = nl ? atomicAdd(&cntG[tid], nl) : 0u;      // one atomic per class
        lcnt[tid] = nl;
    }
    __syncthreads();
    for (int i = tid; i < C_NUM * STG; i += 1024) {
        int c = i >> 5, k = i & (STG - 1);
        if ((u32)k < lcnt[c]) {
            u32 q = lbase[c] + (u32)k;
            if (q < CAP) pool[(size_t)c * CAP + q] = stage[i];
        }
    }
}

// Rank-sort spread over all CUs: grid (C_NUM, 8) x 256. Also zero-fills the
// tail slots [n, TOPK).
__global__ __launch_bounds__(256)
void rank_kernel(const u64* __restrict__ pool, const u32* __restrict__ cntG,
                 const float* __restrict__ anchors, const float* __restrict__ regs,
                 const int* __restrict__ imh, const int* __restrict__ imw,
                 u64* __restrict__ sortedKey, float4* __restrict__ candBox,
                 float* __restrict__ candArea) {
    __shared__ __align__(16) u64 keys[CAP];       // 16 KB
    int c = blockIdx.x, q = blockIdx.y, tid = threadIdx.x;
    int n = (int)cntG[c]; if (n > CAP) n = CAP;
    int my = q * 256 + tid;
    if (my >= n && my < TOPK) {                    // tail zero-fill
        int g = c * TOPK + my;
        sortedKey[g] = 0ull;
        candBox[g] = make_float4(0.f, 0.f, 0.f, 0.f);
        candArea[g] = 0.f;
    }
    if (q * 256 >= n) return;                      // uniform: whole block done
    for (int i = tid; i < n; i += 256) keys[i] = pool[(size_t)c * CAP + i];
    __syncthreads();
    u64 k0 = (my < n) ? keys[my] : ~0ull;          // sentinel: rank 0, write-guarded
    int r0 = 0;
    int j = 0;
    for (; j + 8 <= n; j += 8) {
        ulonglong2 p0 = *(const ulonglong2*)&keys[j];
        ulonglong2 p1 = *(const ulonglong2*)&keys[j + 2];
        ulonglong2 p2 = *(const ulonglong2*)&keys[j + 4];
        ulonglong2 p3 = *(const ulonglong2*)&keys[j + 6];
        r0 += (int)(p0.x > k0) + (int)(p0.y > k0)
            + (int)(p1.x > k0) + (int)(p1.y > k0)
            + (int)(p2.x > k0) + (int)(p2.y > k0)
            + (int)(p3.x > k0) + (int)(p3.y > k0);
    }
    for (; j < n; ++j) r0 += (int)(keys[j] > k0);
    if (my < n && r0 < TOPK) {
        float sc = __uint_as_float((u32)(k0 >> 32));
        int a = (int)(~(u32)k0);
        float fw = (float)(*imw), fh = (float)(*imh);
        float4 bx = make_float4(0.f, 0.f, 0.f, 0.f);
        if (sc > SCORE_THR) decode_box(anchors, regs, a, fw, fh, &bx);
        int g = c * TOPK + r0;
        sortedKey[g] = k0;
        candBox[g] = bx;
        candArea[g] = fmaxf(bx.z - bx.x, 0.0f) * fmaxf(bx.w - bx.y, 0.0f);
    }
}

// Suppression bit-matrix, TRANSPOSED store: supT[c][jw][i] = 64-bit word jw of
// row i (bit j-in-word set iff j>i && iou(i,j)>0.5). Register-resident columns;
// only rows/cols >= rowBase staged into LDS (block q never reads below it).
// Division eliminated: RN32(inter/d) > 0.5f  <=>  inter > (0.5+2^-25)*d (exact in
// double, tie unreachable for f32 operands) -> decisions bit-identical.
__global__ __launch_bounds__(256)
void iou_kernel(const float4* __restrict__ candBox, const float* __restrict__ candArea,
                u64* __restrict__ supT) {
#pragma clang fp contract(off)
    __shared__ float4 box[NCHUNK * 64];           // 16 KB (padded to 1024)
    __shared__ float area[NCHUNK * 64];           //  4 KB
    int c = blockIdx.x, q = blockIdx.y;
    int tid = threadIdx.x, lane = tid & 63, wave = tid >> 6;
    int rowBase = q << 6;
    for (int i = rowBase + tid; i < NCHUNK * 64; i += 256) {
        if (i < TOPK) {
            box[i] = candBox[(size_t)c * TOPK + i];
            area[i] = candArea[(size_t)c * TOPK + i];
        } else {
            box[i] = make_float4(0.f, 0.f, 0.f, 0.f);
            area[i] = 0.f;
        }
    }
    __syncthreads();

    int rowEnd = TOPK - rowBase; if (rowEnd > 64) rowEnd = 64;   // 40 for q=15
    const double CC = 0.5 + 0x1p-25;
    u64* colBase = supT + (size_t)c * (NCHUNK * 1024) + rowBase;

    for (int jw = q + wave; jw < NCHUNK; jw += 4) {
        int j = (jw << 6) | lane;
        float4 bj = box[j];                        // register-resident column
        float aj = area[j];
        u64 vw = 0ull;
#pragma unroll 8
        for (int r = 0; r < 64; ++r) {
            int i = rowBase + r;
            float4 bi = box[i];                    // uniform -> LDS broadcast
            float ai = area[i];
            float ltx = fmaxf(bi.x, bj.x), lty = fmaxf(bi.y, bj.y);
            float rbx = fminf(bi.z, bj.z), rby = fminf(bi.w, bj.w);
            float ww = fmaxf(rbx - ltx, 0.0f), hh = fmaxf(rby - lty, 0.0f);
            float inter = ww * hh;
            float uni = (ai + aj) - inter;
            float d = fmaxf(uni, 1e-8f);
            bool sup = (double)inter > CC * (double)d;
            u64 w64 = __ballot(sup);
            if (jw == q) w64 &= (((~0ull) << 1) << r);   // keep j>i only
            vw = (lane == r) ? w64 : vw;
        }
        if (lane < rowEnd) colBase[(size_t)jw * 1024 + lane] = vw;
    }
}

// Greedy NMS + output, one 1024-thread block per class.
// Phase 1: 1024 threads cooperatively stream the ~69 KB upper-triangle of the
// class's sup matrix into LDS -- thousands of independent u64 loads in flight
// (the MLP that the 64-thread register version couldn't create). One barrier.
// Phase 2: 16-wave chunk loop entirely from LDS: wave w runs the intra-chunk
// closure (readlane chain on a register loaded from LDS), barrier (no vmcnt
// pending -> cheap), waves t>w apply cross-chunk suppression via masked 6-step
// shfl_xor OR-reduce of their coalesced LDS column read. Rows >= TOPK hold
// garbage LDS but their keep bits start 0 and row & -(bit) with bit=0 is a
// no-op -> bit-identical decisions.
__global__ __launch_bounds__(1024)
void nmsout_kernel(const u64* __restrict__ supT, const u64* __restrict__ sortedKey,
                   const float4* __restrict__ candBox, float* __restrict__ out) {
    __shared__ __align__(16) u64 supLds[NCHUNK * 1024];   // 128 KB (triangle filled)
    __shared__ u64 km[NCHUNK];
    int c = blockIdx.x, tid = threadIdx.x;
    int lane = tid & 63, wave = tid >> 6;

    const u64* base = supT + (size_t)c * (NCHUNK * 1024);
#pragma unroll
    for (int jw = 0; jw < NCHUNK; ++jw) {
        int R = (jw + 1) << 6; if (R > TOPK) R = TOPK;    // rows with word jw
        for (int i = tid; i < R; i += 1024)
            supLds[jw * 1024 + i] = base[(size_t)jw * 1024 + i];
    }

    u64 key = (tid < TOPK) ? sortedKey[c * TOPK + tid] : 0ull;
    float sc = __uint_as_float((u32)(key >> 32));
    bool valid = (tid < TOPK) && (sc > SCORE_THR);
    u64 kw = __ballot(valid);                       // wave t's keep word, uniform
    __syncthreads();

    for (int w = 0; w < NCHUNK; ++w) {
        if (wave == w) {
            u64 v = supLds[w * 1024 + (w << 6) + lane];   // row (64w+lane), word w
            u64 am = kw;
#pragma unroll
            for (int i = 0; i < 64; ++i) {
                u64 row = readlane64(v, i);
                am &= ~(row & (0ull - ((am >> i) & 1ull)));
            }
            kw = am;
            if (lane == 0) km[w] = am;
        }
        __syncthreads();
        if (wave > w) {
            u64 kmw = km[w];                              // uniform LDS broadcast
            u64 v = supLds[wave * 1024 + (w << 6) + lane]; // row (64w+lane), word 'wave'
            u64 masked = ((kmw >> lane) & 1ull) ? v : 0ull;
            u32 mlo = (u32)masked, mhi = (u32)(masked >> 32);
#pragma unroll
            for (int s = 1; s < 64; s <<= 1) {
                mlo |= __shfl_xor(mlo, s);
                mhi |= __shfl_xor(mhi, s);
            }
            kw &= ~(((u64)mhi << 32) | mlo);
        }
    }

    if (tid < TOPK) {
        bool keep = (kw >> lane) & 1ull;
        int g = c * TOPK + tid;
        out[g] = keep ? sc : 0.0f;
        out[C_NUM * TOPK + g] = keep ? (float)c : -1.0f;
        float4 b = keep ? candBox[(size_t)c * TOPK + tid]
                        : make_float4(0.f, 0.f, 0.f, 0.f);
        ((float4*)(out + 2 * C_NUM * TOPK))[g] = b;
    }
}

extern "C" void kernel_launch(void* const* d_in, const int* in_sizes, int n_in,
                              void* d_out, int out_size, void* d_ws, size_t ws_size,
                              hipStream_t stream) {
    const float* cls  = (const float*)d_in[0];
    const float* reg  = (const float*)d_in[1];
    const float* anch = (const float*)d_in[2];
    const int* imh    = (const int*)d_in[3];
    const int* imw    = (const int*)d_in[4];
    int A = in_sizes[2] / 4;
    int nvec = (A * C_NUM) / 4;

    char* w = (char*)d_ws;
    size_t off = 0;
    auto alloc = [&](size_t bytes) -> void* {
        off = (off + 255) & ~(size_t)255;
        void* p = w + off;
        off += bytes;
        return p;
    };
    u32*    cntG      = (u32*)   alloc((size_t)C_NUM * 4);
    u32*    thrG      = (u32*)   alloc((size_t)C_NUM * 4);
    u32*    slices    = (u32*)   alloc((size_t)GRID_SCAN * C_NUM * HB * 4);   // 10.5 MB
    u64*    pool      = (u64*)   alloc((size_t)C_NUM * CAP * 8);              // 1.3 MB
    u64*    sortedKey = (u64*)   alloc((size_t)C_NUM * TOPK * 8);
    float4* candBox   = (float4*)alloc((size_t)C_NUM * TOPK * 16);
    float*  candArea  = (float*) alloc((size_t)C_NUM * TOPK * 4);
    u64*    supT      = (u64*)   alloc((size_t)C_NUM * NCHUNK * 1024 * 8);    // 10.5 MB

    hipMemsetAsync(cntG, 0, (size_t)C_NUM * 4, stream);
    hist_kernel<<<GRID_SCAN, 1024, 0, stream>>>((const float4*)cls, slices, nvec);
    thr_kernel<<<C_NUM, 1024, 0, stream>>>(slices, thrG);
    gather_kernel<<<GRID_SCAN, 1024, 0, stream>>>((const float4*)cls, thrG, cntG, pool, nvec);
    rank_kernel<<<dim3(C_NUM, 8), 256, 0, stream>>>(pool, cntG, anch, reg, imh, imw,
                                                    sortedKey, candBox, candArea);
    iou_kernel<<<dim3(C_NUM, NCHUNK), 256, 0, stream>>>(candBox, candArea, supT);
    nmsout_kernel<<<C_NUM, 1024, 0, stream>>>(supT, sortedKey, candBox, (float*)d_out);
}

// Round 14
// 122.613 us; speedup vs baseline: 1.2402x; 1.2380x over previous
//
#include <hip/hip_runtime.h>
#include <hip/hip_bf16.h>
#include <math.h>

typedef unsigned long long u64;
typedef unsigned int u32;

#define C_NUM 80
#define TOPK 1000
#define CAP 2048
#define HB 128
#define STG 32
#define NCHUNK 16
#define SCORE_THR 0.05f
#define IOU_THR 0.5f
#define GRID_SCAN 256

// correctly-rounded-ish f32 exp via double (matched reference bit-exact rounds 1-13)
__device__ __forceinline__ float exp_cr(float x) {
    return (float)exp((double)x);
}

// Exact f32 replication of reference decode + clip (no FMA contraction).
__device__ __forceinline__ void decode_box(const float* __restrict__ anch,
                                           const float* __restrict__ reg,
                                           int a, float fw, float fh, float4* out) {
#pragma clang fp contract(off)
    float a0 = anch[(size_t)a * 4 + 0], a1 = anch[(size_t)a * 4 + 1];
    float a2 = anch[(size_t)a * 4 + 2], a3 = anch[(size_t)a * 4 + 3];
    float d0 = reg[(size_t)a * 4 + 0], d1 = reg[(size_t)a * 4 + 1];
    float d2 = reg[(size_t)a * 4 + 2], d3 = reg[(size_t)a * 4 + 3];
    float w = a2 - a0, h = a3 - a1;
    float cx = a0 + 0.5f * w, cy = a1 + 0.5f * h;
    float dx = d0 * 0.1f, dy = d1 * 0.1f, dw = d2 * 0.2f, dh = d3 * 0.2f;
    float t1 = dx * w; float pcx = cx + t1;
    float t2 = dy * h; float pcy = cy + t2;
    float pw = exp_cr(dw) * w;
    float ph = exp_cr(dh) * h;
    float x1 = pcx - 0.5f * pw, y1 = pcy - 0.5f * ph;
    float x2 = pcx + 0.5f * pw, y2 = pcy + 0.5f * ph;
    x1 = fminf(fmaxf(x1, 0.0f), fw);
    y1 = fminf(fmaxf(y1, 0.0f), fh);
    x2 = fminf(fmaxf(x2, 0.0f), fw);
    y2 = fminf(fmaxf(y2, 0.0f), fh);
    *out = make_float4(x1, y1, x2, y2);
}

// Per-block private histogram slices; no global atomics at all.
__global__ __launch_bounds__(1024)
void hist_kernel(const float4* __restrict__ cls4, u32* __restrict__ slices, int nvec) {
    __shared__ u32 h[C_NUM * HB];                 // 40 KB
    int tid = threadIdx.x;
    for (int i = tid; i < C_NUM * HB; i += 1024) h[i] = 0u;
    __syncthreads();
    int gid = blockIdx.x * 1024 + tid;
    const int stride = GRID_SCAN * 1024;          // float4 units
    const int dC = (stride * 4) % C_NUM;
    int c0 = (gid * 4) % C_NUM;
    for (int v = gid; v < nvec; v += stride) {
        float4 f = cls4[v];
        float e[4] = {f.x, f.y, f.z, f.w};
        int cc = c0;
#pragma unroll
        for (int k = 0; k < 4; ++k) {
            int t = (((int)__float_as_uint(e[k])) - 0x3F000000) >> 16;
            if (t > 0) {
                t = t > HB - 1 ? HB - 1 : t;
                atomicAdd(&h[cc * HB + t], 1u);   // LDS atomic only
            }
            cc++; if (cc == C_NUM) cc = 0;
        }
        c0 += dC; if (c0 >= C_NUM) c0 -= C_NUM;
    }
    __syncthreads();
    u32* my = slices + (size_t)blockIdx.x * (C_NUM * HB);
    for (int i = tid; i < C_NUM * HB; i += 1024) my[i] = h[i];
}

// Per-class: parallel reduce of 256 slices (8 groups x 128 buckets) -> suffix-sum
// -> threshold bit-edge.
__global__ __launch_bounds__(1024)
void thr_kernel(const u32* __restrict__ slices, u32* __restrict__ thrG) {
    __shared__ u32 part[8][HB];
    __shared__ u32 s[HB];
    __shared__ int bsel;
    int c = blockIdx.x, tid = threadIdx.x;
    int b = tid & (HB - 1), g = tid >> 7;         // 8 groups of 32 slices each
    u32 sum = 0;
    const u32* base = slices + c * HB + b;
    for (int sl = g * 32; sl < g * 32 + 32; ++sl)
        sum += base[(size_t)sl * (C_NUM * HB)];   // lanes read consecutive -> coalesced
    part[g][b] = sum;
    if (tid == 0) bsel = 0;
    __syncthreads();
    if (tid < HB) {
        u32 t = 0;
#pragma unroll
        for (int g2 = 0; g2 < 8; ++g2) t += part[g2][tid];
        s[tid] = t;
    }
    __syncthreads();
    for (int d = 1; d < HB; d <<= 1) {
        u32 v = 0;
        if (tid < HB) v = s[tid] + ((tid + d < HB) ? s[tid + d] : 0u);
        __syncthreads();
        if (tid < HB) s[tid] = v;
        __syncthreads();
    }
    if (tid < HB) {
        u32 me = s[tid];
        u32 nxt = (tid < HB - 1) ? s[tid + 1] : 0u;
        if (me >= (u32)TOPK && (tid == HB - 1 || nxt < (u32)TOPK)) bsel = tid;
    }
    __syncthreads();
    if (tid == 0) {
        int bb = bsel;
        thrG[c] = (bb == 0) ? 0u : (u32)(0x3F000000 + (bb << 16));
    }
}

// Gather with block-local LDS staging; ONE bulk reservation atomic per (class,block).
__global__ __launch_bounds__(1024)
void gather_kernel(const float4* __restrict__ cls4, const u32* __restrict__ thrG,
                   u32* __restrict__ cntG, u64* __restrict__ pool, int nvec) {
    __shared__ int thrS[C_NUM];
    __shared__ u32 lcnt[C_NUM];
    __shared__ u32 lbase[C_NUM];
    __shared__ u64 stage[C_NUM * STG];            // 20 KB
    int tid = threadIdx.x;
    if (tid < C_NUM) { thrS[tid] = (int)thrG[tid]; lcnt[tid] = 0u; }
    __syncthreads();

    int gid = blockIdx.x * 1024 + tid;
    const int stride = GRID_SCAN * 1024;
    const int dA = (stride * 4) / C_NUM;
    const int dC = (stride * 4) % C_NUM;
    int base = gid * 4;
    int aa0 = base / C_NUM;
    int c0 = base - aa0 * C_NUM;
    for (int v = gid; v < nvec; v += stride) {
        float4 f = cls4[v];
        float e[4] = {f.x, f.y, f.z, f.w};
        int cc = c0, aa = aa0;
#pragma unroll
        for (int k = 0; k < 4; ++k) {
            int bits = (int)__float_as_uint(e[k]);
            if (bits >= thrS[cc]) {
                u64 key = ((u64)(u32)bits << 32) | (u64)(u32)(~(u32)aa);
                u32 p = atomicAdd(&lcnt[cc], 1u);             // LDS atomic
                if (p < STG) stage[cc * STG + p] = key;
                else {                                         // rare overflow fallback
                    u32 q = atomicAdd(&cntG[cc], 1u);
                    if (q < CAP) pool[(size_t)cc * CAP + q] = key;
                }
            }
            cc++; if (cc == C_NUM) { cc = 0; aa++; }
        }
        c0 += dC;
        if (c0 >= C_NUM) { c0 -= C_NUM; aa0 += dA + 1; } else aa0 += dA;
    }
    __syncthreads();
    if (tid < C_NUM) {
        u32 nl = lcnt[tid]; if (nl > STG) nl = STG;
        lbase[tid] = nl ? atomicAdd(&cntG[tid], nl) : 0u;      // one atomic per class
        lcnt[tid] = nl;
    }
    __syncthreads();
    for (int i = tid; i < C_NUM * STG; i += 1024) {
        int c = i >> 5, k = i & (STG - 1);
        if ((u32)k < lcnt[c]) {
            u32 q = lbase[c] + (u32)k;
            if (q < CAP) pool[(size_t)c * CAP + q] = stage[i];
        }
    }
}

// Rank-sort spread over all CUs: grid (C_NUM, 8) x 256. Also zero-fills the
// tail slots [n, TOPK).
__global__ __launch_bounds__(256)
void rank_kernel(const u64* __restrict__ pool, const u32* __restrict__ cntG,
                 const float* __restrict__ anchors, const float* __restrict__ regs,
                 const int* __restrict__ imh, const int* __restrict__ imw,
                 u64* __restrict__ sortedKey, float4* __restrict__ candBox,
                 float* __restrict__ candArea) {
    __shared__ __align__(16) u64 keys[CAP];       // 16 KB
    int c = blockIdx.x, q = blockIdx.y, tid = threadIdx.x;
    int n = (int)cntG[c]; if (n > CAP) n = CAP;
    int my = q * 256 + tid;
    if (my >= n && my < TOPK) {                    // tail zero-fill
        int g = c * TOPK + my;
        sortedKey[g] = 0ull;
        candBox[g] = make_float4(0.f, 0.f, 0.f, 0.f);
        candArea[g] = 0.f;
    }
    if (q * 256 >= n) return;                      // uniform: whole block done
    for (int i = tid; i < n; i += 256) keys[i] = pool[(size_t)c * CAP + i];
    __syncthreads();
    u64 k0 = (my < n) ? keys[my] : ~0ull;          // sentinel: rank 0, write-guarded
    int r0 = 0;
    int j = 0;
    for (; j + 8 <= n; j += 8) {
        ulonglong2 p0 = *(const ulonglong2*)&keys[j];
        ulonglong2 p1 = *(const ulonglong2*)&keys[j + 2];
        ulonglong2 p2 = *(const ulonglong2*)&keys[j + 4];
        ulonglong2 p3 = *(const ulonglong2*)&keys[j + 6];
        r0 += (int)(p0.x > k0) + (int)(p0.y > k0)
            + (int)(p1.x > k0) + (int)(p1.y > k0)
            + (int)(p2.x > k0) + (int)(p2.y > k0)
            + (int)(p3.x > k0) + (int)(p3.y > k0);
    }
    for (; j < n; ++j) r0 += (int)(keys[j] > k0);
    if (my < n && r0 < TOPK) {
        float sc = __uint_as_float((u32)(k0 >> 32));
        int a = (int)(~(u32)k0);
        float fw = (float)(*imw), fh = (float)(*imh);
        float4 bx = make_float4(0.f, 0.f, 0.f, 0.f);
        if (sc > SCORE_THR) decode_box(anchors, regs, a, fw, fh, &bx);
        int g = c * TOPK + r0;
        sortedKey[g] = k0;
        candBox[g] = bx;
        candArea[g] = fmaxf(bx.z - bx.x, 0.0f) * fmaxf(bx.w - bx.y, 0.0f);
    }
}

// Suppression bit-matrix, TRANSPOSED store: supT[c][jw][i] = 64-bit word jw of
// row i (bit j-in-word set iff j>i && iou(i,j)>0.5). Register-resident columns;
// only rows/cols >= rowBase staged into LDS (block q never reads below it).
// Division eliminated: RN32(inter/d) > 0.5f  <=>  inter > (0.5+2^-25)*d (exact in
// double, tie unreachable for f32 operands) -> decisions bit-identical.
__global__ __launch_bounds__(256)
void iou_kernel(const float4* __restrict__ candBox, const float* __restrict__ candArea,
                u64* __restrict__ supT) {
#pragma clang fp contract(off)
    __shared__ float4 box[NCHUNK * 64];           // 16 KB (padded to 1024)
    __shared__ float area[NCHUNK * 64];           //  4 KB
    int c = blockIdx.x, q = blockIdx.y;
    int tid = threadIdx.x, lane = tid & 63, wave = tid >> 6;
    int rowBase = q << 6;
    for (int i = rowBase + tid; i < NCHUNK * 64; i += 256) {
        if (i < TOPK) {
            box[i] = candBox[(size_t)c * TOPK + i];
            area[i] = candArea[(size_t)c * TOPK + i];
        } else {
            box[i] = make_float4(0.f, 0.f, 0.f, 0.f);
            area[i] = 0.f;
        }
    }
    __syncthreads();

    int rowEnd = TOPK - rowBase; if (rowEnd > 64) rowEnd = 64;   // 40 for q=15
    const double CC = 0.5 + 0x1p-25;
    u64* colBase = supT + (size_t)c * (NCHUNK * 1024) + rowBase;

    for (int jw = q + wave; jw < NCHUNK; jw += 4) {
        int j = (jw << 6) | lane;
        float4 bj = box[j];                        // register-resident column
        float aj = area[j];
        u64 vw = 0ull;
#pragma unroll 8
        for (int r = 0; r < 64; ++r) {
            int i = rowBase + r;
            float4 bi = box[i];                    // uniform -> LDS broadcast
            float ai = area[i];
            float ltx = fmaxf(bi.x, bj.x), lty = fmaxf(bi.y, bj.y);
            float rbx = fminf(bi.z, bj.z), rby = fminf(bi.w, bj.w);
            float ww = fmaxf(rbx - ltx, 0.0f), hh = fmaxf(rby - lty, 0.0f);
            float inter = ww * hh;
            float uni = (ai + aj) - inter;
            float d = fmaxf(uni, 1e-8f);
            bool sup = (double)inter > CC * (double)d;
            u64 w64 = __ballot(sup);
            if (jw == q) w64 &= (((~0ull) << 1) << r);   // keep j>i only
            vw = (lane == r) ? w64 : vw;
        }
        if (lane < rowEnd) colBase[(size_t)jw * 1024 + lane] = vw;
    }
}

// Greedy NMS as a PARALLEL FIXED-POINT iteration (no serial 1000-step chain).
// Greedy keep is the unique fixed point of
//   k[j] = valid[j] & ~OR_{i<j}(k[i] & sup[i][j])
// (unique by induction over the strict i<j order: the smallest differing index
// between two fixed points is determined by the agreeing prefix -> no 2-cycles,
// iteration from k0=valid converges to greedy). Each iteration: wave jw computes
// suppressed word jw = OR over i < 64(jw+1) of supLds[jw][i] & -(keep bit i),
// fully parallel across 16 waves + 6-step shfl_xor reduce. Garbage rows
// (i >= TOPK, unwritten lower triangle) are annihilated by mask = 0.
// Bit-identical to the serial greedy.
__global__ __launch_bounds__(1024)
void nmsout_kernel(const u64* __restrict__ supT, const u64* __restrict__ sortedKey,
                   const float4* __restrict__ candBox, float* __restrict__ out) {
    __shared__ __align__(16) u64 supLds[NCHUNK * 1024];   // 128 KB (triangle filled)
    __shared__ u64 km[NCHUNK];          // current keep words
    __shared__ u64 maskArr[NCHUNK * 64];// 8 KB: -(keep bit i)
    __shared__ int changed;
    int c = blockIdx.x, tid = threadIdx.x;
    int lane = tid & 63, wave = tid >> 6;

    const u64* base = supT + (size_t)c * (NCHUNK * 1024);
#pragma unroll
    for (int jw = 0; jw < NCHUNK; ++jw) {
        int R = (jw + 1) << 6; if (R > TOPK) R = TOPK;    // staged triangle rows
        for (int i = tid; i < R; i += 1024)
            supLds[jw * 1024 + i] = base[(size_t)jw * 1024 + i];
    }

    u64 key = (tid < TOPK) ? sortedKey[c * TOPK + tid] : 0ull;
    float sc = __uint_as_float((u32)(key >> 32));
    bool valid = (tid < TOPK) && (sc > SCORE_THR);
    u64 kwValid = __ballot(valid);                  // wave's valid word (uniform)
    if (lane == 0) km[wave] = kwValid;              // k0 = valid
    if (tid == 0) changed = 1;
    __syncthreads();

    while (changed) {
        // mask per candidate from current keep words (km read; maskArr written)
        maskArr[tid] = 0ull - ((km[wave] >> lane) & 1ull);
        __syncthreads();                            // maskArr ready; km reads done
        if (tid == 0) changed = 0;
        // suppressed word `wave` = OR over contributing rows
        u64 acc = 0ull;
        int R = (wave + 1) << 6;                    // rows i with word `wave` in triangle
        for (int i = lane; i < R; i += 64)
            acc |= supLds[wave * 1024 + i] & maskArr[i];
        u32 lo = (u32)acc, hi = (u32)(acc >> 32);
#pragma unroll
        for (int s = 1; s < 64; s <<= 1) {
            lo |= __shfl_xor(lo, s);
            hi |= __shfl_xor(hi, s);
        }
        u64 nk = kwValid & ~(((u64)hi << 32) | lo);
        __syncthreads();                            // changed reset visible; maskArr reads done
        if (lane == 0) {
            if (nk != km[wave]) changed = 1;        // benign same-value race
            km[wave] = nk;
        }
        __syncthreads();                            // km + changed ready for loop test
    }

    u64 kw = km[wave];
    if (tid < TOPK) {
        bool keep = (kw >> lane) & 1ull;
        int g = c * TOPK + tid;
        out[g] = keep ? sc : 0.0f;
        out[C_NUM * TOPK + g] = keep ? (float)c : -1.0f;
        float4 b = keep ? candBox[(size_t)c * TOPK + tid]
                        : make_float4(0.f, 0.f, 0.f, 0.f);
        ((float4*)(out + 2 * C_NUM * TOPK))[g] = b;
    }
}

extern "C" void kernel_launch(void* const* d_in, const int* in_sizes, int n_in,
                              void* d_out, int out_size, void* d_ws, size_t ws_size,
                              hipStream_t stream) {
    const float* cls  = (const float*)d_in[0];
    const float* reg  = (const float*)d_in[1];
    const float* anch = (const float*)d_in[2];
    const int* imh    = (const int*)d_in[3];
    const int* imw    = (const int*)d_in[4];
    int A = in_sizes[2] / 4;
    int nvec = (A * C_NUM) / 4;

    char* w = (char*)d_ws;
    size_t off = 0;
    auto alloc = [&](size_t bytes) -> void* {
        off = (off + 255) & ~(size_t)255;
        void* p = w + off;
        off += bytes;
        return p;
    };
    u32*    cntG      = (u32*)   alloc((size_t)C_NUM * 4);
    u32*    thrG      = (u32*)   alloc((size_t)C_NUM * 4);
    u32*    slices    = (u32*)   alloc((size_t)GRID_SCAN * C_NUM * HB * 4);   // 10.5 MB
    u64*    pool      = (u64*)   alloc((size_t)C_NUM * CAP * 8);              // 1.3 MB
    u64*    sortedKey = (u64*)   alloc((size_t)C_NUM * TOPK * 8);
    float4* candBox   = (float4*)alloc((size_t)C_NUM * TOPK * 16);
    float*  candArea  = (float*) alloc((size_t)C_NUM * TOPK * 4);
    u64*    supT      = (u64*)   alloc((size_t)C_NUM * NCHUNK * 1024 * 8);    // 10.5 MB

    hipMemsetAsync(cntG, 0, (size_t)C_NUM * 4, stream);
    hist_kernel<<<GRID_SCAN, 1024, 0, stream>>>((const float4*)cls, slices, nvec);
    thr_kernel<<<C_NUM, 1024, 0, stream>>>(slices, thrG);
    gather_kernel<<<GRID_SCAN, 1024, 0, stream>>>((const float4*)cls, thrG, cntG, pool, nvec);
    rank_kernel<<<dim3(C_NUM, 8), 256, 0, stream>>>(pool, cntG, anch, reg, imh, imw,
                                                    sortedKey, candBox, candArea);
    iou_kernel<<<dim3(C_NUM, NCHUNK), 256, 0, stream>>>(candBox, candArea, supT);
    nmsout_kernel<<<C_NUM, 1024, 0, stream>>>(supT, sortedKey, candBox, (float*)d_out);
}

// Round 15
// 119.849 us; speedup vs baseline: 1.2688x; 1.0231x over previous
//
#include <hip/hip_runtime.h>
#include <hip/hip_bf16.h>
#include <math.h>

typedef unsigned long long u64;
typedef unsigned int u32;

#define C_NUM 80
#define TOPK 1000
#define CAP 2048
#define HB 128
#define STG 32
#define NCHUNK 16
#define SCORE_THR 0.05f
#define IOU_THR 0.5f
#define GRID_SCAN 256

// correctly-rounded-ish f32 exp via double (matched reference bit-exact rounds 1-14)
__device__ __forceinline__ float exp_cr(float x) {
    return (float)exp((double)x);
}

// Exact f32 replication of reference decode + clip (no FMA contraction).
__device__ __forceinline__ void decode_box(const float* __restrict__ anch,
                                           const float* __restrict__ reg,
                                           int a, float fw, float fh, float4* out) {
#pragma clang fp contract(off)
    float a0 = anch[(size_t)a * 4 + 0], a1 = anch[(size_t)a * 4 + 1];
    float a2 = anch[(size_t)a * 4 + 2], a3 = anch[(size_t)a * 4 + 3];
    float d0 = reg[(size_t)a * 4 + 0], d1 = reg[(size_t)a * 4 + 1];
    float d2 = reg[(size_t)a * 4 + 2], d3 = reg[(size_t)a * 4 + 3];
    float w = a2 - a0, h = a3 - a1;
    float cx = a0 + 0.5f * w, cy = a1 + 0.5f * h;
    float dx = d0 * 0.1f, dy = d1 * 0.1f, dw = d2 * 0.2f, dh = d3 * 0.2f;
    float t1 = dx * w; float pcx = cx + t1;
    float t2 = dy * h; float pcy = cy + t2;
    float pw = exp_cr(dw) * w;
    float ph = exp_cr(dh) * h;
    float x1 = pcx - 0.5f * pw, y1 = pcy - 0.5f * ph;
    float x2 = pcx + 0.5f * pw, y2 = pcy + 0.5f * ph;
    x1 = fminf(fmaxf(x1, 0.0f), fw);
    y1 = fminf(fmaxf(y1, 0.0f), fh);
    x2 = fminf(fmaxf(x2, 0.0f), fw);
    y2 = fminf(fmaxf(y2, 0.0f), fh);
    *out = make_float4(x1, y1, x2, y2);
}

// Per-block private histogram slices; no global atomics at all.
__global__ __launch_bounds__(1024)
void hist_kernel(const float4* __restrict__ cls4, u32* __restrict__ slices, int nvec) {
    __shared__ u32 h[C_NUM * HB];                 // 40 KB
    int tid = threadIdx.x;
    for (int i = tid; i < C_NUM * HB; i += 1024) h[i] = 0u;
    __syncthreads();
    int gid = blockIdx.x * 1024 + tid;
    const int stride = GRID_SCAN * 1024;          // float4 units
    const int dC = (stride * 4) % C_NUM;
    int c0 = (gid * 4) % C_NUM;
    for (int v = gid; v < nvec; v += stride) {
        float4 f = cls4[v];
        float e[4] = {f.x, f.y, f.z, f.w};
        int cc = c0;
#pragma unroll
        for (int k = 0; k < 4; ++k) {
            int t = (((int)__float_as_uint(e[k])) - 0x3F000000) >> 16;
            if (t > 0) {
                t = t > HB - 1 ? HB - 1 : t;
                atomicAdd(&h[cc * HB + t], 1u);   // LDS atomic only
            }
            cc++; if (cc == C_NUM) cc = 0;
        }
        c0 += dC; if (c0 >= C_NUM) c0 -= C_NUM;
    }
    __syncthreads();
    u32* my = slices + (size_t)blockIdx.x * (C_NUM * HB);
    for (int i = tid; i < C_NUM * HB; i += 1024) my[i] = h[i];
}

// Per-class: parallel reduce of 256 slices (8 groups x 128 buckets) -> suffix-sum
// -> threshold bit-edge.
__global__ __launch_bounds__(1024)
void thr_kernel(const u32* __restrict__ slices, u32* __restrict__ thrG) {
    __shared__ u32 part[8][HB];
    __shared__ u32 s[HB];
    __shared__ int bsel;
    int c = blockIdx.x, tid = threadIdx.x;
    int b = tid & (HB - 1), g = tid >> 7;         // 8 groups of 32 slices each
    u32 sum = 0;
    const u32* base = slices + c * HB + b;
    for (int sl = g * 32; sl < g * 32 + 32; ++sl)
        sum += base[(size_t)sl * (C_NUM * HB)];   // lanes read consecutive -> coalesced
    part[g][b] = sum;
    if (tid == 0) bsel = 0;
    __syncthreads();
    if (tid < HB) {
        u32 t = 0;
#pragma unroll
        for (int g2 = 0; g2 < 8; ++g2) t += part[g2][tid];
        s[tid] = t;
    }
    __syncthreads();
    for (int d = 1; d < HB; d <<= 1) {
        u32 v = 0;
        if (tid < HB) v = s[tid] + ((tid + d < HB) ? s[tid + d] : 0u);
        __syncthreads();
        if (tid < HB) s[tid] = v;
        __syncthreads();
    }
    if (tid < HB) {
        u32 me = s[tid];
        u32 nxt = (tid < HB - 1) ? s[tid + 1] : 0u;
        if (me >= (u32)TOPK && (tid == HB - 1 || nxt < (u32)TOPK)) bsel = tid;
    }
    __syncthreads();
    if (tid == 0) {
        int bb = bsel;
        thrG[c] = (bb == 0) ? 0u : (u32)(0x3F000000 + (bb << 16));
    }
}

// Gather with block-local LDS staging; ONE bulk reservation atomic per (class,block).
__global__ __launch_bounds__(1024)
void gather_kernel(const float4* __restrict__ cls4, const u32* __restrict__ thrG,
                   u32* __restrict__ cntG, u64* __restrict__ pool, int nvec) {
    __shared__ int thrS[C_NUM];
    __shared__ u32 lcnt[C_NUM];
    __shared__ u32 lbase[C_NUM];
    __shared__ u64 stage[C_NUM * STG];            // 20 KB
    int tid = threadIdx.x;
    if (tid < C_NUM) { thrS[tid] = (int)thrG[tid]; lcnt[tid] = 0u; }
    __syncthreads();

    int gid = blockIdx.x * 1024 + tid;
    const int stride = GRID_SCAN * 1024;
    const int dA = (stride * 4) / C_NUM;
    const int dC = (stride * 4) % C_NUM;
    int base = gid * 4;
    int aa0 = base / C_NUM;
    int c0 = base - aa0 * C_NUM;
    for (int v = gid; v < nvec; v += stride) {
        float4 f = cls4[v];
        float e[4] = {f.x, f.y, f.z, f.w};
        int cc = c0, aa = aa0;
#pragma unroll
        for (int k = 0; k < 4; ++k) {
            int bits = (int)__float_as_uint(e[k]);
            if (bits >= thrS[cc]) {
                u64 key = ((u64)(u32)bits << 32) | (u64)(u32)(~(u32)aa);
                u32 p = atomicAdd(&lcnt[cc], 1u);             // LDS atomic
                if (p < STG) stage[cc * STG + p] = key;
                else {                                         // rare overflow fallback
                    u32 q = atomicAdd(&cntG[cc], 1u);
                    if (q < CAP) pool[(size_t)cc * CAP + q] = key;
                }
            }
            cc++; if (cc == C_NUM) { cc = 0; aa++; }
        }
        c0 += dC;
        if (c0 >= C_NUM) { c0 -= C_NUM; aa0 += dA + 1; } else aa0 += dA;
    }
    __syncthreads();
    if (tid < C_NUM) {
        u32 nl = lcnt[tid]; if (nl > STG) nl = STG;
        lbase[tid] = nl ? atomicAdd(&cntG[tid], nl) : 0u;      // one atomic per class
        lcnt[tid] = nl;
    }
    __syncthreads();
    for (int i = tid; i < C_NUM * STG; i += 1024) {
        int c = i >> 5, k = i & (STG - 1);
        if ((u32)k < lcnt[c]) {
            u32 q = lbase[c] + (u32)k;
            if (q < CAP) pool[(size_t)c * CAP + q] = stage[i];
        }
    }
}

// Rank-sort spread over all CUs: grid (C_NUM, 8) x 256. Also zero-fills the
// tail slots [n, TOPK).
__global__ __launch_bounds__(256)
void rank_kernel(const u64* __restrict__ pool, const u32* __restrict__ cntG,
                 const float* __restrict__ anchors, const float* __restrict__ regs,
                 const int* __restrict__ imh, const int* __restrict__ imw,
                 u64* __restrict__ sortedKey, float4* __restrict__ candBox,
                 float* __restrict__ candArea) {
    __shared__ __align__(16) u64 keys[CAP];       // 16 KB
    int c = blockIdx.x, q = blockIdx.y, tid = threadIdx.x;
    int n = (int)cntG[c]; if (n > CAP) n = CAP;
    int my = q * 256 + tid;
    if (my >= n && my < TOPK) {                    // tail zero-fill
        int g = c * TOPK + my;
        sortedKey[g] = 0ull;
        candBox[g] = make_float4(0.f, 0.f, 0.f, 0.f);
        candArea[g] = 0.f;
    }
    if (q * 256 >= n) return;                      // uniform: whole block done
    for (int i = tid; i < n; i += 256) keys[i] = pool[(size_t)c * CAP + i];
    __syncthreads();
    u64 k0 = (my < n) ? keys[my] : ~0ull;          // sentinel: rank 0, write-guarded
    int r0 = 0;
    int j = 0;
    for (; j + 8 <= n; j += 8) {
        ulonglong2 p0 = *(const ulonglong2*)&keys[j];
        ulonglong2 p1 = *(const ulonglong2*)&keys[j + 2];
        ulonglong2 p2 = *(const ulonglong2*)&keys[j + 4];
        ulonglong2 p3 = *(const ulonglong2*)&keys[j + 6];
        r0 += (int)(p0.x > k0) + (int)(p0.y > k0)
            + (int)(p1.x > k0) + (int)(p1.y > k0)
            + (int)(p2.x > k0) + (int)(p2.y > k0)
            + (int)(p3.x > k0) + (int)(p3.y > k0);
    }
    for (; j < n; ++j) r0 += (int)(keys[j] > k0);
    if (my < n && r0 < TOPK) {
        float sc = __uint_as_float((u32)(k0 >> 32));
        int a = (int)(~(u32)k0);
        float fw = (float)(*imw), fh = (float)(*imh);
        float4 bx = make_float4(0.f, 0.f, 0.f, 0.f);
        if (sc > SCORE_THR) decode_box(anchors, regs, a, fw, fh, &bx);
        int g = c * TOPK + r0;
        sortedKey[g] = k0;
        candBox[g] = bx;
        candArea[g] = fmaxf(bx.z - bx.x, 0.0f) * fmaxf(bx.w - bx.y, 0.0f);
    }
}

// Suppression bit-matrix, TRANSPOSED store: supT[c][jw][i] = word jw of row i
// (bit j-in-word set iff j>i && iou(i,j)>0.5).
// Balanced: the 136 (row-chunk q, word jw>=q) pairs are distributed flat over
// 17 blocks x 4 waves = 68 waves/class, exactly 2 pairs per wave.
// f64 ELIMINATED: RN32(inter/d) > 0.5f  <=>  (inter+inter) > d in plain f32.
// Proof: RN(q)>0.5 <=> q > 0.5+2^-25 (tie rounds even to 0.5); with A=2*inter
// exact, A > d*(1+2^-24) <=> A > d as floats, since d*2^-24 in [ulp(d)/2,ulp(d))
// strictly and A = d*(1+2^-24) exactly is impossible (2^24+1 odd > 24-bit
// significand). Subnormal inter cannot flip either side (threshold >= 5e-9).
// -> decisions bit-identical to the reference f32 division.
__global__ __launch_bounds__(256)
void iou_kernel(const float4* __restrict__ candBox, const float* __restrict__ candArea,
                u64* __restrict__ supT) {
#pragma clang fp contract(off)
    __shared__ float4 box[NCHUNK * 64];           // 16 KB (padded to 1024)
    __shared__ float area[NCHUNK * 64];           //  4 KB
    int c = blockIdx.x, bq = blockIdx.y;          // bq in [0,17)
    int tid = threadIdx.x, lane = tid & 63, wave = tid >> 6;
    for (int i = tid; i < NCHUNK * 64; i += 256) {
        if (i < TOPK) {
            box[i] = candBox[(size_t)c * TOPK + i];
            area[i] = candArea[(size_t)c * TOPK + i];
        } else {
            box[i] = make_float4(0.f, 0.f, 0.f, 0.f);
            area[i] = 0.f;
        }
    }
    __syncthreads();

    u64* clsBase = supT + (size_t)c * (NCHUNK * 1024);
    int wgl = bq * 4 + wave;                      // [0,68)

#pragma unroll
    for (int pp = 0; pp < 2; ++pp) {
        int p = wgl + pp * 68;                    // [0,136)
        // triangular decode: (q, jw) with jw >= q; counts 16-q per q
        int q = 0, rem = p;
        while (rem >= NCHUNK - q) { rem -= NCHUNK - q; ++q; }
        int jw = q + rem;

        int rowBase = q << 6;
        int j = (jw << 6) | lane;
        float4 bj = box[j];                        // register-resident column
        float aj = area[j];
        u64 vw = 0ull;
#pragma unroll 8
        for (int r = 0; r < 64; ++r) {
            int i = rowBase + r;
            float4 bi = box[i];                    // uniform -> LDS broadcast
            float ai = area[i];
            float ltx = fmaxf(bi.x, bj.x), lty = fmaxf(bi.y, bj.y);
            float rbx = fminf(bi.z, bj.z), rby = fminf(bi.w, bj.w);
            float ww = fmaxf(rbx - ltx, 0.0f), hh = fmaxf(rby - lty, 0.0f);
            float inter = ww * hh;
            float uni = (ai + aj) - inter;
            float d = fmaxf(uni, 1e-8f);
            bool sup = (inter + inter) > d;        // == RN32(inter/d) > 0.5f
            u64 w64 = __ballot(sup);
            if (jw == q) w64 &= (((~0ull) << 1) << r);   // keep j>i only
            vw = (lane == r) ? w64 : vw;
        }
        int rowEnd = TOPK - rowBase; if (rowEnd > 64) rowEnd = 64;
        if (lane < rowEnd) clsBase[(size_t)jw * 1024 + rowBase + lane] = vw;
    }
}

// Greedy NMS as a PARALLEL FIXED-POINT iteration (no serial 1000-step chain).
// Greedy keep is the unique fixed point of
//   k[j] = valid[j] & ~OR_{i<j}(k[i] & sup[i][j])
// (unique by induction over i<j order). Iterate from k0=valid; wave jw computes
// suppressed word jw via 16 parallel waves + 6-step shfl_xor reduce. Garbage
// rows (i >= TOPK) are annihilated by mask = 0. Bit-identical to serial greedy.
__global__ __launch_bounds__(1024)
void nmsout_kernel(const u64* __restrict__ supT, const u64* __restrict__ sortedKey,
                   const float4* __restrict__ candBox, float* __restrict__ out) {
    __shared__ __align__(16) u64 supLds[NCHUNK * 1024];   // 128 KB (triangle filled)
    __shared__ u64 km[NCHUNK];          // current keep words
    __shared__ u64 maskArr[NCHUNK * 64];// 8 KB: -(keep bit i)
    __shared__ int changed;
    int c = blockIdx.x, tid = threadIdx.x;
    int lane = tid & 63, wave = tid >> 6;

    const u64* base = supT + (size_t)c * (NCHUNK * 1024);
#pragma unroll
    for (int jw = 0; jw < NCHUNK; ++jw) {
        int R = (jw + 1) << 6; if (R > TOPK) R = TOPK;    // staged triangle rows
        for (int i = tid; i < R; i += 1024)
            supLds[jw * 1024 + i] = base[(size_t)jw * 1024 + i];
    }

    u64 key = (tid < TOPK) ? sortedKey[c * TOPK + tid] : 0ull;
    float sc = __uint_as_float((u32)(key >> 32));
    bool valid = (tid < TOPK) && (sc > SCORE_THR);
    u64 kwValid = __ballot(valid);                  // wave's valid word (uniform)
    if (lane == 0) km[wave] = kwValid;              // k0 = valid
    if (tid == 0) changed = 1;
    __syncthreads();

    while (changed) {
        maskArr[tid] = 0ull - ((km[wave] >> lane) & 1ull);
        __syncthreads();                            // maskArr ready; km reads done
        if (tid == 0) changed = 0;
        u64 acc = 0ull;
        int R = (wave + 1) << 6;
        for (int i = lane; i < R; i += 64)
            acc |= supLds[wave * 1024 + i] & maskArr[i];
        u32 lo = (u32)acc, hi = (u32)(acc >> 32);
#pragma unroll
        for (int s = 1; s < 64; s <<= 1) {
            lo |= __shfl_xor(lo, s);
            hi |= __shfl_xor(hi, s);
        }
        u64 nk = kwValid & ~(((u64)hi << 32) | lo);
        __syncthreads();                            // changed reset visible
        if (lane == 0) {
            if (nk != km[wave]) changed = 1;        // benign same-value race
            km[wave] = nk;
        }
        __syncthreads();                            // km + changed ready
    }

    u64 kw = km[wave];
    if (tid < TOPK) {
        bool keep = (kw >> lane) & 1ull;
        int g = c * TOPK + tid;
        out[g] = keep ? sc : 0.0f;
        out[C_NUM * TOPK + g] = keep ? (float)c : -1.0f;
        float4 b = keep ? candBox[(size_t)c * TOPK + tid]
                        : make_float4(0.f, 0.f, 0.f, 0.f);
        ((float4*)(out + 2 * C_NUM * TOPK))[g] = b;
    }
}

extern "C" void kernel_launch(void* const* d_in, const int* in_sizes, int n_in,
                              void* d_out, int out_size, void* d_ws, size_t ws_size,
                              hipStream_t stream) {
    const float* cls  = (const float*)d_in[0];
    const float* reg  = (const float*)d_in[1];
    const float* anch = (const float*)d_in[2];
    const int* imh    = (const int*)d_in[3];
    const int* imw    = (const int*)d_in[4];
    int A = in_sizes[2] / 4;
    int nvec = (A * C_NUM) / 4;

    char* w = (char*)d_ws;
    size_t off = 0;
    auto alloc = [&](size_t bytes) -> void* {
        off = (off + 255) & ~(size_t)255;
        void* p = w + off;
        off += bytes;
        return p;
    };
    u32*    cntG      = (u32*)   alloc((size_t)C_NUM * 4);
    u32*    thrG      = (u32*)   alloc((size_t)C_NUM * 4);
    u32*    slices    = (u32*)   alloc((size_t)GRID_SCAN * C_NUM * HB * 4);   // 10.5 MB
    u64*    pool      = (u64*)   alloc((size_t)C_NUM * CAP * 8);              // 1.3 MB
    u64*    sortedKey = (u64*)   alloc((size_t)C_NUM * TOPK * 8);
    float4* candBox   = (float4*)alloc((size_t)C_NUM * TOPK * 16);
    float*  candArea  = (float*) alloc((size_t)C_NUM * TOPK * 4);
    u64*    supT      = (u64*)   alloc((size_t)C_NUM * NCHUNK * 1024 * 8);    // 10.5 MB

    hipMemsetAsync(cntG, 0, (size_t)C_NUM * 4, stream);
    hist_kernel<<<GRID_SCAN, 1024, 0, stream>>>((const float4*)cls, slices, nvec);
    thr_kernel<<<C_NUM, 1024, 0, stream>>>(slices, thrG);
    gather_kernel<<<GRID_SCAN, 1024, 0, stream>>>((const float4*)cls, thrG, cntG, pool, nvec);
    rank_kernel<<<dim3(C_NUM, 8), 256, 0, stream>>>(pool, cntG, anch, reg, imh, imw,
                                                    sortedKey, candBox, candArea);
    iou_kernel<<<dim3(C_NUM, 17), 256, 0, stream>>>(candBox, candArea, supT);
    nmsout_kernel<<<C_NUM, 1024, 0, stream>>>(supT, sortedKey, candBox, (float*)d_out);
}

// Round 16
// 107.094 us; speedup vs baseline: 1.4199x; 1.1191x over previous
//
#include <hip/hip_runtime.h>
#include <hip/hip_bf16.h>
#include <math.h>

typedef unsigned long long u64;
typedef unsigned int u32;

#define C_NUM 80
#define TOPK 1000
#define CAP 2048
#define HB 128
#define STG 32
#define NCHUNK 16
#define SCORE_THR 0.05f
#define IOU_THR 0.5f
#define GRID_SCAN 256

// correctly-rounded-ish f32 exp via double (matched reference bit-exact rounds 1-15)
__device__ __forceinline__ float exp_cr(float x) {
    return (float)exp((double)x);
}

// Exact f32 replication of reference decode + clip (no FMA contraction).
__device__ __forceinline__ void decode_box(const float* __restrict__ anch,
                                           const float* __restrict__ reg,
                                           int a, float fw, float fh, float4* out) {
#pragma clang fp contract(off)
    float a0 = anch[(size_t)a * 4 + 0], a1 = anch[(size_t)a * 4 + 1];
    float a2 = anch[(size_t)a * 4 + 2], a3 = anch[(size_t)a * 4 + 3];
    float d0 = reg[(size_t)a * 4 + 0], d1 = reg[(size_t)a * 4 + 1];
    float d2 = reg[(size_t)a * 4 + 2], d3 = reg[(size_t)a * 4 + 3];
    float w = a2 - a0, h = a3 - a1;
    float cx = a0 + 0.5f * w, cy = a1 + 0.5f * h;
    float dx = d0 * 0.1f, dy = d1 * 0.1f, dw = d2 * 0.2f, dh = d3 * 0.2f;
    float t1 = dx * w; float pcx = cx + t1;
    float t2 = dy * h; float pcy = cy + t2;
    float pw = exp_cr(dw) * w;
    float ph = exp_cr(dh) * h;
    float x1 = pcx - 0.5f * pw, y1 = pcy - 0.5f * ph;
    float x2 = pcx + 0.5f * pw, y2 = pcy + 0.5f * ph;
    x1 = fminf(fmaxf(x1, 0.0f), fw);
    y1 = fminf(fmaxf(y1, 0.0f), fh);
    x2 = fminf(fmaxf(x2, 0.0f), fw);
    y2 = fminf(fmaxf(y2, 0.0f), fh);
    *out = make_float4(x1, y1, x2, y2);
}

// Per-block private histogram slices; no global atomics. Block 0 also zeroes
// cntG (replaces the hipMemsetAsync launch; gather runs two launches later).
__global__ __launch_bounds__(1024)
void hist_kernel(const float4* __restrict__ cls4, u32* __restrict__ slices,
                 u32* __restrict__ cntG, int nvec) {
    __shared__ u32 h[C_NUM * HB];                 // 40 KB
    int tid = threadIdx.x;
    if (blockIdx.x == 0 && tid < C_NUM) cntG[tid] = 0u;
    for (int i = tid; i < C_NUM * HB; i += 1024) h[i] = 0u;
    __syncthreads();
    int gid = blockIdx.x * 1024 + tid;
    const int stride = GRID_SCAN * 1024;          // float4 units
    const int dC = (stride * 4) % C_NUM;
    int c0 = (gid * 4) % C_NUM;
    for (int v = gid; v < nvec; v += stride) {
        float4 f = cls4[v];
        float e[4] = {f.x, f.y, f.z, f.w};
        int cc = c0;
#pragma unroll
        for (int k = 0; k < 4; ++k) {
            int t = (((int)__float_as_uint(e[k])) - 0x3F000000) >> 16;
            if (t > 0) {
                t = t > HB - 1 ? HB - 1 : t;
                atomicAdd(&h[cc * HB + t], 1u);   // LDS atomic only
            }
            cc++; if (cc == C_NUM) cc = 0;
        }
        c0 += dC; if (c0 >= C_NUM) c0 -= C_NUM;
    }
    __syncthreads();
    u32* my = slices + (size_t)blockIdx.x * (C_NUM * HB);
    for (int i = tid; i < C_NUM * HB; i += 1024) my[i] = h[i];
}

// Per-class: parallel reduce of 256 slices (8 groups x 128 buckets) -> suffix-sum
// -> threshold bit-edge.
__global__ __launch_bounds__(1024)
void thr_kernel(const u32* __restrict__ slices, u32* __restrict__ thrG) {
    __shared__ u32 part[8][HB];
    __shared__ u32 s[HB];
    __shared__ int bsel;
    int c = blockIdx.x, tid = threadIdx.x;
    int b = tid & (HB - 1), g = tid >> 7;         // 8 groups of 32 slices each
    u32 sum = 0;
    const u32* base = slices + c * HB + b;
    for (int sl = g * 32; sl < g * 32 + 32; ++sl)
        sum += base[(size_t)sl * (C_NUM * HB)];   // lanes read consecutive -> coalesced
    part[g][b] = sum;
    if (tid == 0) bsel = 0;
    __syncthreads();
    if (tid < HB) {
        u32 t = 0;
#pragma unroll
        for (int g2 = 0; g2 < 8; ++g2) t += part[g2][tid];
        s[tid] = t;
    }
    __syncthreads();
    for (int d = 1; d < HB; d <<= 1) {
        u32 v = 0;
        if (tid < HB) v = s[tid] + ((tid + d < HB) ? s[tid + d] : 0u);
        __syncthreads();
        if (tid < HB) s[tid] = v;
        __syncthreads();
    }
    if (tid < HB) {
        u32 me = s[tid];
        u32 nxt = (tid < HB - 1) ? s[tid + 1] : 0u;
        if (me >= (u32)TOPK && (tid == HB - 1 || nxt < (u32)TOPK)) bsel = tid;
    }
    __syncthreads();
    if (tid == 0) {
        int bb = bsel;
        thrG[c] = (bb == 0) ? 0u : (u32)(0x3F000000 + (bb << 16));
    }
}

// Gather with block-local LDS staging; ONE bulk reservation atomic per (class,block).
__global__ __launch_bounds__(1024)
void gather_kernel(const float4* __restrict__ cls4, const u32* __restrict__ thrG,
                   u32* __restrict__ cntG, u64* __restrict__ pool, int nvec) {
    __shared__ int thrS[C_NUM];
    __shared__ u32 lcnt[C_NUM];
    __shared__ u32 lbase[C_NUM];
    __shared__ u64 stage[C_NUM * STG];            // 20 KB
    int tid = threadIdx.x;
    if (tid < C_NUM) { thrS[tid] = (int)thrG[tid]; lcnt[tid] = 0u; }
    __syncthreads();

    int gid = blockIdx.x * 1024 + tid;
    const int stride = GRID_SCAN * 1024;
    const int dA = (stride * 4) / C_NUM;
    const int dC = (stride * 4) % C_NUM;
    int base = gid * 4;
    int aa0 = base / C_NUM;
    int c0 = base - aa0 * C_NUM;
    for (int v = gid; v < nvec; v += stride) {
        float4 f = cls4[v];
        float e[4] = {f.x, f.y, f.z, f.w};
        int cc = c0, aa = aa0;
#pragma unroll
        for (int k = 0; k < 4; ++k) {
            int bits = (int)__float_as_uint(e[k]);
            if (bits >= thrS[cc]) {
                u64 key = ((u64)(u32)bits << 32) | (u64)(u32)(~(u32)aa);
                u32 p = atomicAdd(&lcnt[cc], 1u);             // LDS atomic
                if (p < STG) stage[cc * STG + p] = key;
                else {                                         // rare overflow fallback
                    u32 q = atomicAdd(&cntG[cc], 1u);
                    if (q < CAP) pool[(size_t)cc * CAP + q] = key;
                }
            }
            cc++; if (cc == C_NUM) { cc = 0; aa++; }
        }
        c0 += dC;
        if (c0 >= C_NUM) { c0 -= C_NUM; aa0 += dA + 1; } else aa0 += dA;
    }
    __syncthreads();
    if (tid < C_NUM) {
        u32 nl = lcnt[tid]; if (nl > STG) nl = STG;
        lbase[tid] = nl ? atomicAdd(&cntG[tid], nl) : 0u;      // one atomic per class
        lcnt[tid] = nl;
    }
    __syncthreads();
    for (int i = tid; i < C_NUM * STG; i += 1024) {
        int c = i >> 5, k = i & (STG - 1);
        if ((u32)k < lcnt[c]) {
            u32 q = lbase[c] + (u32)k;
            if (q < CAP) pool[(size_t)c * CAP + q] = stage[i];
        }
    }
}

// Rank-sort spread over all CUs: grid (C_NUM, 8) x 256. Also zero-fills the
// tail slots [n, TOPK).
__global__ __launch_bounds__(256)
void rank_kernel(const u64* __restrict__ pool, const u32* __restrict__ cntG,
                 const float* __restrict__ anchors, const float* __restrict__ regs,
                 const int* __restrict__ imh, const int* __restrict__ imw,
                 u64* __restrict__ sortedKey, float4* __restrict__ candBox,
                 float* __restrict__ candArea) {
    __shared__ __align__(16) u64 keys[CAP];       // 16 KB
    int c = blockIdx.x, q = blockIdx.y, tid = threadIdx.x;
    int n = (int)cntG[c]; if (n > CAP) n = CAP;
    int my = q * 256 + tid;
    if (my >= n && my < TOPK) {                    // tail zero-fill
        int g = c * TOPK + my;
        sortedKey[g] = 0ull;
        candBox[g] = make_float4(0.f, 0.f, 0.f, 0.f);
        candArea[g] = 0.f;
    }
    if (q * 256 >= n) return;                      // uniform: whole block done
    for (int i = tid; i < n; i += 256) keys[i] = pool[(size_t)c * CAP + i];
    __syncthreads();
    u64 k0 = (my < n) ? keys[my] : ~0ull;          // sentinel: rank 0, write-guarded
    int r0 = 0;
    int j = 0;
    for (; j + 8 <= n; j += 8) {
        ulonglong2 p0 = *(const ulonglong2*)&keys[j];
        ulonglong2 p1 = *(const ulonglong2*)&keys[j + 2];
        ulonglong2 p2 = *(const ulonglong2*)&keys[j + 4];
        ulonglong2 p3 = *(const ulonglong2*)&keys[j + 6];
        r0 += (int)(p0.x > k0) + (int)(p0.y > k0)
            + (int)(p1.x > k0) + (int)(p1.y > k0)
            + (int)(p2.x > k0) + (int)(p2.y > k0)
            + (int)(p3.x > k0) + (int)(p3.y > k0);
    }
    for (; j < n; ++j) r0 += (int)(keys[j] > k0);
    if (my < n && r0 < TOPK) {
        float sc = __uint_as_float((u32)(k0 >> 32));
        int a = (int)(~(u32)k0);
        float fw = (float)(*imw), fh = (float)(*imh);
        float4 bx = make_float4(0.f, 0.f, 0.f, 0.f);
        if (sc > SCORE_THR) decode_box(anchors, regs, a, fw, fh, &bx);
        int g = c * TOPK + r0;
        sortedKey[g] = k0;
        candBox[g] = bx;
        candArea[g] = fmaxf(bx.z - bx.x, 0.0f) * fmaxf(bx.w - bx.y, 0.0f);
    }
}

// Suppression bit-matrix, TRANSPOSED store: supT[c][jw][i] = word jw of row i
// (bit j-in-word set iff j>i && iou(i,j)>0.5).
// DUAL-COLUMN waves: each wave owns TWO word-columns (jwA,jwB=jwA+1) of one
// row-chunk q -- bi/ai LDS reads, lane==r select and loop overhead amortize
// over 2 columns, and the two independent IoU chains double ILP. 72 wave-tasks
// = sum over q of ceil((16-q)/2); grid (80,9) x 512 (8 waves). The diagonal
// word (jw==q) is always column A (pairIdx==0), masked with bits lane>r.
// f32-only compare: RN32(inter/d) > 0.5f  <=>  (inter+inter) > d (proof: tie
// 0.5+2^-25 rounds even to 0.5; A=2*inter exact; A > d*(1+2^-24) <=> A > d as
// floats since d*2^-24 in [ulp(d)/2, ulp(d)) and A = d*(1+2^-24) exactly is
// impossible). Decisions bit-identical to the reference f32 division.
__global__ __launch_bounds__(512)
void iou_kernel(const float4* __restrict__ candBox, const float* __restrict__ candArea,
                u64* __restrict__ supT) {
#pragma clang fp contract(off)
    __shared__ float4 box[NCHUNK * 64];           // 16 KB (padded to 1024)
    __shared__ float area[NCHUNK * 64];           //  4 KB
    int c = blockIdx.x, bq = blockIdx.y;          // bq in [0,9)
    int tid = threadIdx.x, lane = tid & 63, wave = tid >> 6;   // 8 waves
    for (int i = tid; i < NCHUNK * 64; i += 512) {
        if (i < TOPK) {
            box[i] = candBox[(size_t)c * TOPK + i];
            area[i] = candArea[(size_t)c * TOPK + i];
        } else {
            box[i] = make_float4(0.f, 0.f, 0.f, 0.f);
            area[i] = 0.f;
        }
    }
    __syncthreads();

    int wid = bq * 8 + wave;                      // [0,72)
    int q = 0, rem = wid;
    while (rem >= ((17 - q) >> 1)) { rem -= (17 - q) >> 1; ++q; }
    int jwA = q + 2 * rem;
    int jwB = jwA + 1;
    bool hasB = (jwB < NCHUNK);
    bool diag = (rem == 0);                       // jwA == q

    int rowBase = q << 6;
    int jA = (jwA << 6) | lane;
    int jB = hasB ? ((jwB << 6) | lane) : jA;
    float4 bjA = box[jA]; float ajA = area[jA];   // register-resident columns
    float4 bjB = box[jB]; float ajB = area[jB];
    u64 vwA = 0ull, vwB = 0ull;

#pragma unroll 16
    for (int r = 0; r < 64; ++r) {
        int i = rowBase + r;
        float4 bi = box[i];                       // uniform -> LDS broadcast
        float ai = area[i];
        // column A
        float ltxA = fmaxf(bi.x, bjA.x), ltyA = fmaxf(bi.y, bjA.y);
        float rbxA = fminf(bi.z, bjA.z), rbyA = fminf(bi.w, bjA.w);
        float wwA = fmaxf(rbxA - ltxA, 0.0f), hhA = fmaxf(rbyA - ltyA, 0.0f);
        float interA = wwA * hhA;
        float dA = fmaxf((ai + ajA) - interA, 1e-8f);
        bool supA = (interA + interA) > dA;       // == RN32(inter/d) > 0.5f
        // column B
        float ltxB = fmaxf(bi.x, bjB.x), ltyB = fmaxf(bi.y, bjB.y);
        float rbxB = fminf(bi.z, bjB.z), rbyB = fminf(bi.w, bjB.w);
        float wwB = fmaxf(rbxB - ltxB, 0.0f), hhB = fmaxf(rbyB - ltyB, 0.0f);
        float interB = wwB * hhB;
        float dB = fmaxf((ai + ajB) - interB, 1e-8f);
        bool supB = (interB + interB) > dB;

        u64 wA = __ballot(supA);
        u64 wB = __ballot(supB);
        if (diag) wA &= (((~0ull) << 1) << r);    // keep j>i only (uniform branch)
        bool sel = (lane == r);
        vwA = sel ? wA : vwA;
        vwB = sel ? wB : vwB;
    }

    int rowEnd = TOPK - rowBase; if (rowEnd > 64) rowEnd = 64;
    u64* clsBase = supT + (size_t)c * (NCHUNK * 1024);
    if (lane < rowEnd) {
        clsBase[(size_t)jwA * 1024 + rowBase + lane] = vwA;
        if (hasB) clsBase[(size_t)jwB * 1024 + rowBase + lane] = vwB;
    }
}

// Greedy NMS as a PARALLEL FIXED-POINT iteration (no serial 1000-step chain).
// Greedy keep is the unique fixed point of
//   k[j] = valid[j] & ~OR_{i<j}(k[i] & sup[i][j])
// (unique by induction over i<j order). Iterate from k0=valid; wave jw computes
// suppressed word jw via 16 parallel waves + 6-step shfl_xor reduce. Garbage
// rows (i >= TOPK) are annihilated by mask = 0. Bit-identical to serial greedy.
__global__ __launch_bounds__(1024)
void nmsout_kernel(const u64* __restrict__ supT, const u64* __restrict__ sortedKey,
                   const float4* __restrict__ candBox, float* __restrict__ out) {
    __shared__ __align__(16) u64 supLds[NCHUNK * 1024];   // 128 KB (triangle filled)
    __shared__ u64 km[NCHUNK];          // current keep words
    __shared__ u64 maskArr[NCHUNK * 64];// 8 KB: -(keep bit i)
    __shared__ int changed;
    int c = blockIdx.x, tid = threadIdx.x;
    int lane = tid & 63, wave = tid >> 6;

    const u64* base = supT + (size_t)c * (NCHUNK * 1024);
#pragma unroll
    for (int jw = 0; jw < NCHUNK; ++jw) {
        int R = (jw + 1) << 6; if (R > TOPK) R = TOPK;    // staged triangle rows
        for (int i = tid; i < R; i += 1024)
            supLds[jw * 1024 + i] = base[(size_t)jw * 1024 + i];
    }

    u64 key = (tid < TOPK) ? sortedKey[c * TOPK + tid] : 0ull;
    float sc = __uint_as_float((u32)(key >> 32));
    bool valid = (tid < TOPK) && (sc > SCORE_THR);
    u64 kwValid = __ballot(valid);                  // wave's valid word (uniform)
    if (lane == 0) km[wave] = kwValid;              // k0 = valid
    if (tid == 0) changed = 1;
    __syncthreads();

    while (changed) {
        maskArr[tid] = 0ull - ((km[wave] >> lane) & 1ull);
        __syncthreads();                            // maskArr ready; km reads done
        if (tid == 0) changed = 0;
        u64 acc = 0ull;
        int R = (wave + 1) << 6;
        for (int i = lane; i < R; i += 64)
            acc |= supLds[wave * 1024 + i] & maskArr[i];
        u32 lo = (u32)acc, hi = (u32)(acc >> 32);
#pragma unroll
        for (int s = 1; s < 64; s <<= 1) {
            lo |= __shfl_xor(lo, s);
            hi |= __shfl_xor(hi, s);
        }
        u64 nk = kwValid & ~(((u64)hi << 32) | lo);
        __syncthreads();                            // changed reset visible
        if (lane == 0) {
            if (nk != km[wave]) changed = 1;        // benign same-value race
            km[wave] = nk;
        }
        __syncthreads();                            // km + changed ready
    }

    u64 kw = km[wave];
    if (tid < TOPK) {
        bool keep = (kw >> lane) & 1ull;
        int g = c * TOPK + tid;
        out[g] = keep ? sc : 0.0f;
        out[C_NUM * TOPK + g] = keep ? (float)c : -1.0f;
        float4 b = keep ? candBox[(size_t)c * TOPK + tid]
                        : make_float4(0.f, 0.f, 0.f, 0.f);
        ((float4*)(out + 2 * C_NUM * TOPK))[g] = b;
    }
}

extern "C" void kernel_launch(void* const* d_in, const int* in_sizes, int n_in,
                              void* d_out, int out_size, void* d_ws, size_t ws_size,
                              hipStream_t stream) {
    const float* cls  = (const float*)d_in[0];
    const float* reg  = (const float*)d_in[1];
    const float* anch = (const float*)d_in[2];
    const int* imh    = (const int*)d_in[3];
    const int* imw    = (const int*)d_in[4];
    int A = in_sizes[2] / 4;
    int nvec = (A * C_NUM) / 4;

    char* w = (char*)d_ws;
    size_t off = 0;
    auto alloc = [&](size_t bytes) -> void* {
        off = (off + 255) & ~(size_t)255;
        void* p = w + off;
        off += bytes;
        return p;
    };
    u32*    cntG      = (u32*)   alloc((size_t)C_NUM * 4);
    u32*    thrG      = (u32*)   alloc((size_t)C_NUM * 4);
    u32*    slices    = (u32*)   alloc((size_t)GRID_SCAN * C_NUM * HB * 4);   // 10.5 MB
    u64*    pool      = (u64*)   alloc((size_t)C_NUM * CAP * 8);              // 1.3 MB
    u64*    sortedKey = (u64*)   alloc((size_t)C_NUM * TOPK * 8);
    float4* candBox   = (float4*)alloc((size_t)C_NUM * TOPK * 16);
    float*  candArea  = (float*) alloc((size_t)C_NUM * TOPK * 4);
    u64*    supT      = (u64*)   alloc((size_t)C_NUM * NCHUNK * 1024 * 8);    // 10.5 MB

    hist_kernel<<<GRID_SCAN, 1024, 0, stream>>>((const float4*)cls, slices, cntG, nvec);
    thr_kernel<<<C_NUM, 1024, 0, stream>>>(slices, thrG);
    gather_kernel<<<GRID_SCAN, 1024, 0, stream>>>((const float4*)cls, thrG, cntG, pool, nvec);
    rank_kernel<<<dim3(C_NUM, 8), 256, 0, stream>>>(pool, cntG, anch, reg, imh, imw,
                                                    sortedKey, candBox, candArea);
    iou_kernel<<<dim3(C_NUM, 9), 512, 0, stream>>>(candBox, candArea, supT);
    nmsout_kernel<<<C_NUM, 1024, 0, stream>>>(supT, sortedKey, candBox, (float*)d_out);
}